// Round 7
// baseline (106.614 us; speedup 1.0000x reference)
//
#include <hip/hip_runtime.h>

#define NQ 10
#define QD 6
#define DIN 512
#define DOUT 64

typedef float v2f __attribute__((ext_vector_type(2)));

__device__ __forceinline__ v2f sp(float s) { v2f r; r.x = s; r.y = s; return r; }
__device__ __forceinline__ v2f mk(float a, float b) { v2f r; r.x = a; r.y = b; return r; }

// ---- forced packed-fp32 (VOP3P) ops -----------------------------------
__device__ __forceinline__ v2f pk_fma(v2f a, v2f b, v2f c) {
    v2f d; asm("v_pk_fma_f32 %0, %1, %2, %3" : "=v"(d) : "v"(a), "v"(b), "v"(c)); return d;
}
__device__ __forceinline__ v2f pk_mul(v2f a, v2f b) {
    v2f d; asm("v_pk_mul_f32 %0, %1, %2" : "=v"(d) : "v"(a), "v"(b)); return d;
}
__device__ __forceinline__ v2f pk_add(v2f a, v2f b) {
    v2f d; asm("v_pk_add_f32 %0, %1, %2" : "=v"(d) : "v"(a), "v"(b)); return d;
}

// ---- cross-lane helpers -------------------------------------------------
// xor1=quad_perm[1,0,3,2]; xor2=quad_perm[2,3,0,1]; xor4=row_half_mirror o
// quad_perm[3,2,1,0]; xor8=row_ror:8; xor16=ds_swizzle; xor32=ds_bpermute.
template <int CTRL>
__device__ __forceinline__ float dppf(float v) {
    return __int_as_float(__builtin_amdgcn_mov_dpp(__float_as_int(v), CTRL, 0xF, 0xF, true));
}
template <int M>
__device__ __forceinline__ float sx(float v) {
    if constexpr (M == 1)       return dppf<0xB1>(v);
    else if constexpr (M == 2)  return dppf<0x4E>(v);
    else if constexpr (M == 4)  return dppf<0x1B>(dppf<0x141>(v));
    else if constexpr (M == 8)  return dppf<0x128>(v);
    else                        return __int_as_float(__builtin_amdgcn_ds_swizzle(__float_as_int(v), 0x401F));
}
__device__ __forceinline__ float sx32(float v, int xaddr) {
    return __int_as_float(__builtin_amdgcn_ds_bpermute(xaddr, __float_as_int(v)));
}
template <int M>
__device__ __forceinline__ v2f sx2(v2f v) { return mk(sx<M>(v.x), sx<M>(v.y)); }
__device__ __forceinline__ float red64(float v, int xaddr) {
    v += dppf<0x128>(v);   // row_ror:8
    v += dppf<0x124>(v);   // row_ror:4
    v += dppf<0x122>(v);   // row_ror:2
    v += dppf<0x121>(v);   // row_ror:1
    v += __int_as_float(__builtin_amdgcn_ds_swizzle(__float_as_int(v), 0x401F));
    v += sx32(v, xaddr);
    return v;
}

// One wave64 = one sample. Amp idx = (lane<<4) | (m<<1) | comp, m = 0..7.
// Wires 0..5 = lane bits 5..0; wires 6,7,8 = m bits 2,1,0; wire 9 = comp.
// CNOT fusion:
//   pre-CNOT+RY : (al,be) = cbit ? ( g, C) : (C, g),  g = tbit ? S : -S
//   RY+post-CNOT: (al,be) = cbit ? (-g, C) : (C, g)
// Even phase: w0, w2+preC12, w4+preC34, w6+preC56, w8+preC78
// Odd  phase: w1+postC01, w3+postC23, w5+postC45, w7+postC67, w9+postC89
// E_0 folded into initial state (bit relabel).
// launch_bounds(256, 6): cap 85 VGPRs — R6's (256,8)=64-cap caused scratch
// spills (WRITE_SIZE 2->8 MB); loop live-set ~60 regs fits under 85.
__global__ __launch_bounds__(256, 6) void dqc_main(
    const float* __restrict__ x,
    const float* __restrict__ W1,
    const float* __restrict__ b1,
    const float* __restrict__ qw,
    const float* __restrict__ W2,
    const float* __restrict__ b2,
    float* __restrict__ out,
    const int B)
{
    // per layer (stride 24 floats for b128 alignment):
    // [C0,S0,C2,S2,C4,S4,C6,S6,C8,S8, pad2, C1,S1,C3,S3,C5,S5,C7,S7,C9,S9, pad2]
    __shared__ __align__(16) float csl[QD * 24];

    const int tid = threadIdx.x;
    if (tid < QD * NQ) {
        const int layer = tid / NQ, wire = tid - layer * NQ;
        float s, c;
        sincosf(qw[tid] * 0.5f, &s, &c);
        const int pos = layer * 24 + (wire & 1) * 12 + (wire >> 1) * 2;
        csl[pos] = c; csl[pos + 1] = s;
    }

    const int lane = tid & 63;
    const int b = blockIdx.x * 4 + (tid >> 6);
    const int bb = (b < B) ? b : (B - 1);
    const int xaddr = ((tid ^ 32) & 63) << 2;   // bpermute addr: lane^32

    // ---------- front-end: dot = x[b,:] @ W1 ----------
    float xr[8];
    {
        const float4* xp = (const float4*)(x + (size_t)bb * DIN + lane * 8);
        const float4 v0 = xp[0], v1 = xp[1];
        xr[0]=v0.x; xr[1]=v0.y; xr[2]=v0.z; xr[3]=v0.w;
        xr[4]=v1.x; xr[5]=v1.y; xr[6]=v1.z; xr[7]=v1.w;
    }
    float dot[NQ];
    #pragma unroll
    for (int w = 0; w < NQ; ++w) dot[w] = 0.f;
    {
        // lane handles W1 rows [8*lane, +8); 2 rows = 20 floats = 5 float4
        const float4* wp = (const float4*)(W1 + (size_t)lane * 8 * NQ);
        #pragma unroll
        for (int j = 0; j < 4; ++j) {
            const float4 f0 = wp[5*j], f1 = wp[5*j+1], f2 = wp[5*j+2],
                         f3 = wp[5*j+3], f4 = wp[5*j+4];
            const float xa = xr[2*j], xb = xr[2*j+1];
            dot[0]=fmaf(xa,f0.x,dot[0]); dot[1]=fmaf(xa,f0.y,dot[1]);
            dot[2]=fmaf(xa,f0.z,dot[2]); dot[3]=fmaf(xa,f0.w,dot[3]);
            dot[4]=fmaf(xa,f1.x,dot[4]); dot[5]=fmaf(xa,f1.y,dot[5]);
            dot[6]=fmaf(xa,f1.z,dot[6]); dot[7]=fmaf(xa,f1.w,dot[7]);
            dot[8]=fmaf(xa,f2.x,dot[8]); dot[9]=fmaf(xa,f2.y,dot[9]);
            dot[0]=fmaf(xb,f2.z,dot[0]); dot[1]=fmaf(xb,f2.w,dot[1]);
            dot[2]=fmaf(xb,f3.x,dot[2]); dot[3]=fmaf(xb,f3.y,dot[3]);
            dot[4]=fmaf(xb,f3.z,dot[4]); dot[5]=fmaf(xb,f3.w,dot[5]);
            dot[6]=fmaf(xb,f4.x,dot[6]); dot[7]=fmaf(xb,f4.y,dot[7]);
            dot[8]=fmaf(xb,f4.z,dot[8]); dot[9]=fmaf(xb,f4.w,dot[9]);
        }
    }
    #pragma unroll
    for (int w = 0; w < NQ; ++w) dot[w] = red64(dot[w], xaddr);

    float u0[NQ], u1[NQ];
    #pragma unroll
    for (int w = 0; w < NQ; ++w) {
        const float th2 = tanhf(dot[w] + b1[w]) * 0.78539816339744830962f;  // pi/4
        float s, c;
        sincosf(th2, &s, &c);
        const float isq2 = 0.70710678118654752440f;
        u0[w] = (c - s) * isq2;
        u1[w] = (c + s) * isq2;
    }

    // ---------- initial product state with E_0 folded (bit relabel) ----------
    // w0@b5, w1@b4^b5, w2@b3, w3@b2^b3, w4@b1, w5@b0^b1,
    // w6@m2, w7@m1^m2, w8@m0, w9@comp^m0
    v2f A[8];
    {
        float lf = ((lane & 32) ? u1[0] : u0[0]);
        lf *= ((((lane >> 4) ^ (lane >> 5)) & 1) ? u1[1] : u0[1]);
        lf *= ((lane & 8) ? u1[2] : u0[2]);
        lf *= ((((lane >> 2) ^ (lane >> 3)) & 1) ? u1[3] : u0[3]);
        lf *= ((lane & 2) ? u1[4] : u0[4]);
        lf *= (((lane ^ (lane >> 1)) & 1) ? u1[5] : u0[5]);
        #pragma unroll
        for (int m = 0; m < 8; ++m) {
            float f = ((m & 4) ? u1[6] : u0[6]);
            f *= ((((m >> 1) ^ (m >> 2)) & 1) ? u1[7] : u0[7]);
            f *= ((m & 1) ? u1[8] : u0[8]);
            f *= lf;
            A[m] = (m & 1) ? mk(f * u1[9], f * u0[9]) : mk(f * u0[9], f * u1[9]);
        }
    }

    __syncthreads();  // csl ready (no early return above)

    // ---------- 6 fused layers ----------
    #pragma unroll 1
    for (int k = 0; k < QD; ++k) {
        const float* ce = csl + k * 24;
        const bool fuse = (k != QD - 1);

        const float4 ea = *(const float4*)(ce);
        const float4 eb = *(const float4*)(ce + 4);
        const float2 ec = *(const float2*)(ce + 8);
        const float C0=ea.x, S0=ea.y, C2=ea.z, S2=ea.w;
        const float C4=eb.x, S4=eb.y, C6=eb.z, S6=eb.w;
        const float C8=ec.x, S8=ec.y;

        {   // w0 plain: partner lane^32 (bpermute)
            const float g = (lane & 32) ? S0 : -S0;
            const v2f alv = sp(C0), bev = sp(g);
            #pragma unroll
            for (int m = 0; m < 8; ++m) {
                const v2f p = mk(sx32(A[m].x, xaddr), sx32(A[m].y, xaddr));
                A[m] = pk_fma(alv, A[m], pk_mul(bev, p));
            }
        }
        {   // w2 + pre C(1,2): partner lane^8, ctrl lane b4
            const float g = (lane & 8) ? S2 : -S2;
            const bool cb = (lane & 16) != 0;
            const v2f alv = sp(cb ? g : C2), bev = sp(cb ? C2 : g);
            #pragma unroll
            for (int m = 0; m < 8; ++m) {
                const v2f p = sx2<8>(A[m]);
                A[m] = pk_fma(alv, A[m], pk_mul(bev, p));
            }
        }
        {   // w4 + pre C(3,4): partner lane^2, ctrl lane b2
            const float g = (lane & 2) ? S4 : -S4;
            const bool cb = (lane & 4) != 0;
            const v2f alv = sp(cb ? g : C4), bev = sp(cb ? C4 : g);
            #pragma unroll
            for (int m = 0; m < 8; ++m) {
                const v2f p = sx2<2>(A[m]);
                A[m] = pk_fma(alv, A[m], pk_mul(bev, p));
            }
        }
        {   // w6 + pre C(5,6): reg pairs (m, m+4), ctrl lane b0 (runtime)
            const bool cb = (lane & 1) != 0;
            const v2f a_lo = sp(cb ? -S6 : C6), b_lo = sp(cb ? C6 : -S6);
            const v2f a_hi = sp(cb ?  S6 : C6), b_hi = sp(cb ? C6 :  S6);
            #pragma unroll
            for (int m = 0; m < 4; ++m) {
                const v2f lo = A[m], hi = A[m + 4];
                A[m]     = pk_fma(a_lo, lo, pk_mul(b_lo, hi));
                A[m + 4] = pk_fma(a_hi, hi, pk_mul(b_hi, lo));
            }
        }
        {   // w8 + pre C(7,8): reg pairs (m, m+1) m even, ctrl m1 (compile-time)
            const v2f c8 = sp(C8), s8 = sp(S8), ns8 = sp(-S8);
            #pragma unroll
            for (int m = 0; m < 8; m += 2) {
                const v2f lo = A[m], hi = A[m + 1];
                if (m & 2) {
                    A[m]     = pk_fma(ns8, lo, pk_mul(c8, hi));
                    A[m + 1] = pk_fma(s8,  hi, pk_mul(c8, lo));
                } else {
                    A[m]     = pk_fma(c8, lo, pk_mul(ns8, hi));
                    A[m + 1] = pk_fma(c8, hi, pk_mul(s8,  lo));
                }
            }
        }

        const float4 oa = *(const float4*)(ce + 12);
        const float4 ob = *(const float4*)(ce + 16);
        const float2 oc = *(const float2*)(ce + 20);
        const float C1=oa.x, S1=oa.y, C3=oa.z, S3=oa.w;
        const float C5=ob.x, S5=ob.y, C7=ob.z, S7=ob.w;
        const float C9=oc.x, S9=oc.y;

        {   // w1 + post C(0,1): partner lane^16 (swizzle), ctrl lane b5
            const float g = (lane & 16) ? S1 : -S1;
            const bool cb = fuse && ((lane & 32) != 0);
            const v2f alv = sp(cb ? -g : C1), bev = sp(cb ? C1 : g);
            #pragma unroll
            for (int m = 0; m < 8; ++m) {
                const v2f p = sx2<16>(A[m]);
                A[m] = pk_fma(alv, A[m], pk_mul(bev, p));
            }
        }
        {   // w3 + post C(2,3): partner lane^4 (dual DPP), ctrl lane b3
            const float g = (lane & 4) ? S3 : -S3;
            const bool cb = fuse && ((lane & 8) != 0);
            const v2f alv = sp(cb ? -g : C3), bev = sp(cb ? C3 : g);
            #pragma unroll
            for (int m = 0; m < 8; ++m) {
                const v2f p = sx2<4>(A[m]);
                A[m] = pk_fma(alv, A[m], pk_mul(bev, p));
            }
        }
        {   // w5 + post C(4,5): partner lane^1, ctrl lane b1
            const float g = (lane & 1) ? S5 : -S5;
            const bool cb = fuse && ((lane & 2) != 0);
            const v2f alv = sp(cb ? -g : C5), bev = sp(cb ? C5 : g);
            #pragma unroll
            for (int m = 0; m < 8; ++m) {
                const v2f p = sx2<1>(A[m]);
                A[m] = pk_fma(alv, A[m], pk_mul(bev, p));
            }
        }
        {   // w7 + post C(6,7): reg pairs (m, m+2), ctrl m2 (compile-time + fuse)
            const v2f c7 = sp(C7), s7 = sp(S7), ns7 = sp(-S7);
            const v2f a_lo4 = fuse ? s7 : c7,  b_lo4 = fuse ? c7 : ns7;
            const v2f a_hi4 = fuse ? ns7 : c7, b_hi4 = fuse ? c7 : s7;
            #pragma unroll
            for (int m = 0; m < 2; ++m) {
                {   const v2f lo = A[m], hi = A[m + 2];
                    A[m]     = pk_fma(c7, lo, pk_mul(ns7, hi));
                    A[m + 2] = pk_fma(c7, hi, pk_mul(s7,  lo)); }
                {   const v2f lo = A[m + 4], hi = A[m + 6];
                    A[m + 4] = pk_fma(a_lo4, lo, pk_mul(b_lo4, hi));
                    A[m + 6] = pk_fma(a_hi4, hi, pk_mul(b_hi4, lo)); }
            }
        }
        {   // w9 + post C(8,9): in-v2f pair, ctrl m0 (compile-time + fuse)
            const float nS9 = -S9;
            const float axx = fuse ? S9 : C9,  axy = fuse ? C9 : nS9;
            const float ayy = fuse ? nS9 : C9, ayx = fuse ? C9 : S9;
            #pragma unroll
            for (int m = 0; m < 8; ++m) {
                const float ax = A[m].x, ay = A[m].y;
                if (m & 1) {
                    A[m].x = fmaf(axx, ax, axy * ay);
                    A[m].y = fmaf(ayy, ay, ayx * ax);
                } else {
                    A[m].x = fmaf(C9, ax, nS9 * ay);
                    A[m].y = fmaf(C9, ay, S9  * ax);
                }
            }
        }
    }

    // ---------- expvals <Z_w> ----------
    v2f P[8];
    #pragma unroll
    for (int m = 0; m < 8; ++m) P[m] = pk_mul(A[m], A[m]);
    const v2f s01 = pk_add(P[0], P[1]), s23 = pk_add(P[2], P[3]);
    const v2f s45 = pk_add(P[4], P[5]), s67 = pk_add(P[6], P[7]);
    const v2f q8v = pk_add(pk_add(P[1], P[3]), pk_add(P[5], P[7]));
    const v2f q6v = pk_add(s45, s67);
    const v2f q7v = pk_add(s23, s67);
    const v2f tot2 = pk_add(pk_add(s01, s23), q6v);
    const float tot = tot2.x + tot2.y;

    float e[NQ];
    e[0] = (lane & 32) ? -tot : tot;
    e[1] = (lane & 16) ? -tot : tot;
    e[2] = (lane & 8)  ? -tot : tot;
    e[3] = (lane & 4)  ? -tot : tot;
    e[4] = (lane & 2)  ? -tot : tot;
    e[5] = (lane & 1)  ? -tot : tot;
    e[6] = fmaf(-2.f, q6v.x + q6v.y, tot);
    e[7] = fmaf(-2.f, q7v.x + q7v.y, tot);
    e[8] = fmaf(-2.f, q8v.x + q8v.y, tot);
    e[9] = fmaf(-2.f, tot2.y, tot);
    #pragma unroll
    for (int w = 0; w < NQ; ++w) e[w] = red64(e[w], xaddr);

    // ---------- output GEMM: lane = output column ----------
    if (b < B) {
        float o = b2[lane];
        #pragma unroll
        for (int w = 0; w < NQ; ++w) o = fmaf(e[w], W2[w * DOUT + lane], o);
        out[(size_t)b * DOUT + lane] = o;
    }
}

extern "C" void kernel_launch(void* const* d_in, const int* in_sizes, int n_in,
                              void* d_out, int out_size, void* d_ws, size_t ws_size,
                              hipStream_t stream) {
    const float* x  = (const float*)d_in[0];
    const float* W1 = (const float*)d_in[1];
    const float* b1 = (const float*)d_in[2];
    const float* qw = (const float*)d_in[3];
    const float* W2 = (const float*)d_in[4];
    const float* b2 = (const float*)d_in[5];
    float* out = (float*)d_out;

    const int B = in_sizes[0] / DIN;
    const int blocks = (B + 3) / 4;   // 4 samples (waves) per 256-thread block
    dqc_main<<<blocks, 256, 0, stream>>>(x, W1, b1, qw, W2, b2, out, B);
}

// Round 8
// 105.759 us; speedup vs baseline: 1.0081x; 1.0081x over previous
//
#include <hip/hip_runtime.h>

#define NQ 10
#define QD 6
#define DIN 512
#define DOUT 64

// ---- fused shuffle+FMA: t += dpp(a) * b  (DPP applies to src0 only) ----
// Hazard discipline: any VGPR read as DPP src0 must be >=2 VALU instrs from
// its last write. We guarantee >=16 via mul-block / sched_barrier / fmac-block.
#define FMAC_DPP(t, a, b, CTRL) \
    asm("v_fmac_f32_dpp %0, %1, %2 " CTRL " row_mask:0xf bank_mask:0xf" \
        : "+v"(t) : "v"(a), "v"(b))
#define SB() __builtin_amdgcn_sched_barrier(0)

// DPP-gate: A[r] = alv*A[r] + bev*xor_dpp(A[r]) for 16 state floats.
#define LANE_GATE_DPP(CTRL, ALV, BEV)                                     \
    {                                                                     \
        float t[16];                                                      \
        _Pragma("unroll")                                                 \
        for (int r = 0; r < 16; ++r) t[r] = (ALV) * A[r];                 \
        SB();                                                             \
        _Pragma("unroll")                                                 \
        for (int r = 0; r < 16; ++r) FMAC_DPP(t[r], A[r], (BEV), CTRL);   \
        SB();                                                             \
        _Pragma("unroll")                                                 \
        for (int r = 0; r < 16; ++r) A[r] = t[r];                         \
    }

// xor4 gate = row_half_mirror (xor7) then quad_perm[3,2,1,0] (xor3) fused.
#define LANE_GATE_X4(ALV, BEV)                                            \
    {                                                                     \
        float p[16], t[16];                                               \
        _Pragma("unroll")                                                 \
        for (int r = 0; r < 16; ++r) p[r] = dppf<0x141>(A[r]);            \
        SB();                                                             \
        _Pragma("unroll")                                                 \
        for (int r = 0; r < 16; ++r) t[r] = (ALV) * A[r];                 \
        SB();                                                             \
        _Pragma("unroll")                                                 \
        for (int r = 0; r < 16; ++r)                                      \
            FMAC_DPP(t[r], p[r], (BEV), "quad_perm:[3,2,1,0]");           \
        SB();                                                             \
        _Pragma("unroll")                                                 \
        for (int r = 0; r < 16; ++r) A[r] = t[r];                         \
    }

template <int CTRL>
__device__ __forceinline__ float dppf(float v) {
    return __int_as_float(__builtin_amdgcn_mov_dpp(__float_as_int(v), CTRL, 0xF, 0xF, true));
}
template <int M>
__device__ __forceinline__ float sx(float v) {
    if constexpr (M == 16)
        return __int_as_float(__builtin_amdgcn_ds_swizzle(__float_as_int(v), 0x401F));
}
__device__ __forceinline__ float sx32(float v, int xaddr) {
    return __int_as_float(__builtin_amdgcn_ds_bpermute(xaddr, __float_as_int(v)));
}
__device__ __forceinline__ float red64(float v, int xaddr) {
    v += dppf<0x128>(v);   // row_ror:8
    v += dppf<0x124>(v);   // row_ror:4
    v += dppf<0x122>(v);   // row_ror:2
    v += dppf<0x121>(v);   // row_ror:1
    v += __int_as_float(__builtin_amdgcn_ds_swizzle(__float_as_int(v), 0x401F));
    v += sx32(v, xaddr);
    return v;
}

__device__ __forceinline__ float tanh_fast(float x) {
    const float e = __expf(2.0f * x);
    return 1.0f - __fdividef(2.0f, e + 1.0f);
}

// One wave64 = one sample. Amp idx = (lane<<4) | r; r bits: b3=w6, b2=w7,
// b1=w8, b0=w9. Wires 0..5 = lane bits 5..0.
// CNOT fusion (validated R3..R7):
//   pre-CNOT+RY : (al,be) = cbit ? ( g, C) : (C, g),  g = tbit ? S : -S
//   RY+post-CNOT: (al,be) = cbit ? (-g, C) : (C, g)
// Even phase: w0, w2+preC12, w4+preC34, w6+preC56, w8+preC78
// Odd  phase: w1+postC01, w3+postC23, w5+postC45, w7+postC67, w9+postC89
// E_0 folded into the initial state (bit relabel).
__global__ __launch_bounds__(256, 4) void dqc_main(
    const float* __restrict__ x,
    const float* __restrict__ W1,
    const float* __restrict__ b1,
    const float* __restrict__ qw,
    const float* __restrict__ W2,
    const float* __restrict__ b2,
    float* __restrict__ out,
    const int B)
{
    // per layer (stride 24 floats):
    // [C0,S0,C2,S2,C4,S4,C6,S6,C8,S8,pad2, C1,S1,C3,S3,C5,S5,C7,S7,C9,S9,pad2]
    __shared__ __align__(16) float csl[QD * 24];

    const int tid = threadIdx.x;
    if (tid < QD * NQ) {
        const int layer = tid / NQ, wire = tid - layer * NQ;
        const float h = qw[tid] * 0.5f;
        const int pos = layer * 24 + (wire & 1) * 12 + (wire >> 1) * 2;
        csl[pos] = __cosf(h); csl[pos + 1] = __sinf(h);
    }

    const int lane = tid & 63;
    const int b = blockIdx.x * 4 + (tid >> 6);
    const int bb = (b < B) ? b : (B - 1);
    const int xaddr = ((tid ^ 32) & 63) << 2;   // bpermute addr: lane^32

    // ---------- front-end: dot = x[b,:] @ W1 ----------
    float xr[8];
    {
        const float4* xp = (const float4*)(x + (size_t)bb * DIN + lane * 8);
        const float4 v0 = xp[0], v1 = xp[1];
        xr[0]=v0.x; xr[1]=v0.y; xr[2]=v0.z; xr[3]=v0.w;
        xr[4]=v1.x; xr[5]=v1.y; xr[6]=v1.z; xr[7]=v1.w;
    }
    float dot[NQ];
    #pragma unroll
    for (int w = 0; w < NQ; ++w) dot[w] = 0.f;
    {
        const float4* wp = (const float4*)(W1 + (size_t)lane * 8 * NQ);
        #pragma unroll
        for (int j = 0; j < 4; ++j) {
            const float4 f0 = wp[5*j], f1 = wp[5*j+1], f2 = wp[5*j+2],
                         f3 = wp[5*j+3], f4 = wp[5*j+4];
            const float xa = xr[2*j], xb = xr[2*j+1];
            dot[0]=fmaf(xa,f0.x,dot[0]); dot[1]=fmaf(xa,f0.y,dot[1]);
            dot[2]=fmaf(xa,f0.z,dot[2]); dot[3]=fmaf(xa,f0.w,dot[3]);
            dot[4]=fmaf(xa,f1.x,dot[4]); dot[5]=fmaf(xa,f1.y,dot[5]);
            dot[6]=fmaf(xa,f1.z,dot[6]); dot[7]=fmaf(xa,f1.w,dot[7]);
            dot[8]=fmaf(xa,f2.x,dot[8]); dot[9]=fmaf(xa,f2.y,dot[9]);
            dot[0]=fmaf(xb,f2.z,dot[0]); dot[1]=fmaf(xb,f2.w,dot[1]);
            dot[2]=fmaf(xb,f3.x,dot[2]); dot[3]=fmaf(xb,f3.y,dot[3]);
            dot[4]=fmaf(xb,f3.z,dot[4]); dot[5]=fmaf(xb,f3.w,dot[5]);
            dot[6]=fmaf(xb,f4.x,dot[6]); dot[7]=fmaf(xb,f4.y,dot[7]);
            dot[8]=fmaf(xb,f4.z,dot[8]); dot[9]=fmaf(xb,f4.w,dot[9]);
        }
    }
    #pragma unroll
    for (int w = 0; w < NQ; ++w) dot[w] = red64(dot[w], xaddr);

    // u0 = cos(th2+pi/4), u1 = sin(th2+pi/4), th2 = tanh(dot+b1)*pi/4
    float u0[NQ], u1[NQ];
    #pragma unroll
    for (int w = 0; w < NQ; ++w) {
        const float phi = fmaf(tanh_fast(dot[w] + b1[w]),
                               0.78539816339744830962f, 0.78539816339744830962f);
        u0[w] = __cosf(phi);
        u1[w] = __sinf(phi);
    }

    // ---------- initial product state with E_0 folded (bit relabel) ----------
    // w0@b5, w1@b4^b5, w2@b3, w3@b2^b3, w4@b1, w5@b0^b1 (lane);
    // w6@r3, w7@r2^r3, w8@r1, w9@r0^r1 (register)
    float A[16];
    {
        float lf = ((lane & 32) ? u1[0] : u0[0]);
        lf *= ((((lane >> 4) ^ (lane >> 5)) & 1) ? u1[1] : u0[1]);
        lf *= ((lane & 8) ? u1[2] : u0[2]);
        lf *= ((((lane >> 2) ^ (lane >> 3)) & 1) ? u1[3] : u0[3]);
        lf *= ((lane & 2) ? u1[4] : u0[4]);
        lf *= (((lane ^ (lane >> 1)) & 1) ? u1[5] : u0[5]);
        #pragma unroll
        for (int r = 0; r < 16; ++r) {
            float f = ((r & 8) ? u1[6] : u0[6]);
            f *= ((((r >> 2) ^ (r >> 3)) & 1) ? u1[7] : u0[7]);
            f *= ((r & 2) ? u1[8] : u0[8]);
            f *= ((((r >> 1) ^ r) & 1) ? u1[9] : u0[9]);
            A[r] = f * lf;
        }
    }

    __syncthreads();  // csl ready (no early return above)

    // ---------- 6 fused layers ----------
    #pragma unroll 1
    for (int k = 0; k < QD; ++k) {
        const float* ce = csl + k * 24;
        const bool fuse = (k != QD - 1);

        const float4 ea = *(const float4*)(ce);
        const float4 eb = *(const float4*)(ce + 4);
        const float2 ec = *(const float2*)(ce + 8);
        const float C0=ea.x,S0=ea.y, C2=ea.z,S2=ea.w;
        const float C4=eb.x,S4=eb.y, C6=eb.z,S6=eb.w;
        const float C8=ec.x,S8=ec.y;

        {   // w0 plain: partner lane^32 (bpermute)
            const float g = (lane & 32) ? S0 : -S0;
            float p[16];
            #pragma unroll
            for (int r = 0; r < 16; ++r) p[r] = sx32(A[r], xaddr);
            #pragma unroll
            for (int r = 0; r < 16; ++r) A[r] = fmaf(C0, A[r], g * p[r]);
        }
        {   // w2 + pre C(1,2): xor8 (row_ror:8), ctrl lane b4
            const float g = (lane & 8) ? S2 : -S2;
            const bool cb = (lane & 16) != 0;
            const float alv = cb ? g : C2, bev = cb ? C2 : g;
            LANE_GATE_DPP("row_ror:8", alv, bev);
        }
        {   // w4 + pre C(3,4): xor2 (quad_perm), ctrl lane b2
            const float g = (lane & 2) ? S4 : -S4;
            const bool cb = (lane & 4) != 0;
            const float alv = cb ? g : C4, bev = cb ? C4 : g;
            LANE_GATE_DPP("quad_perm:[2,3,0,1]", alv, bev);
        }
        {   // w6 + pre C(5,6): reg pairs (r, r+8), ctrl lane b0 (runtime)
            const bool cb = (lane & 1) != 0;
            const float a_lo = cb ? -S6 : C6, b_lo = cb ? C6 : -S6;
            const float a_hi = cb ?  S6 : C6, b_hi = cb ? C6 :  S6;
            #pragma unroll
            for (int r = 0; r < 8; ++r) {
                const float lo = A[r], hi = A[r + 8];
                A[r]     = fmaf(a_lo, lo, b_lo * hi);
                A[r + 8] = fmaf(a_hi, hi, b_hi * lo);
            }
        }
        {   // w8 + pre C(7,8): reg pairs (r, r+2), ctrl r bit2 (compile-time)
            #pragma unroll
            for (int r = 0; r < 16; ++r) {
                if (r & 2) continue;
                const float lo = A[r], hi = A[r + 2];
                if (r & 4) {
                    A[r]     = fmaf(-S8, lo, C8 * hi);
                    A[r + 2] = fmaf( S8, hi, C8 * lo);
                } else {
                    A[r]     = fmaf(C8, lo, -S8 * hi);
                    A[r + 2] = fmaf(C8, hi,  S8 * lo);
                }
            }
        }

        const float4 oa = *(const float4*)(ce + 12);
        const float4 ob = *(const float4*)(ce + 16);
        const float2 oc = *(const float2*)(ce + 20);
        const float C1=oa.x,S1=oa.y, C3=oa.z,S3=oa.w;
        const float C5=ob.x,S5=ob.y, C7=ob.z,S7=ob.w;
        const float C9=oc.x,S9=oc.y;

        {   // w1 + post C(0,1): xor16 (ds_swizzle), ctrl lane b5
            const float g = (lane & 16) ? S1 : -S1;
            const bool cb = fuse && ((lane & 32) != 0);
            const float alv = cb ? -g : C1, bev = cb ? C1 : g;
            float p[16];
            #pragma unroll
            for (int r = 0; r < 16; ++r) p[r] = sx<16>(A[r]);
            #pragma unroll
            for (int r = 0; r < 16; ++r) A[r] = fmaf(alv, A[r], bev * p[r]);
        }
        {   // w3 + post C(2,3): xor4 (mirror + fused quad_perm), ctrl lane b3
            const float g = (lane & 4) ? S3 : -S3;
            const bool cb = fuse && ((lane & 8) != 0);
            const float alv = cb ? -g : C3, bev = cb ? C3 : g;
            LANE_GATE_X4(alv, bev);
        }
        {   // w5 + post C(4,5): xor1 (quad_perm), ctrl lane b1
            const float g = (lane & 1) ? S5 : -S5;
            const bool cb = fuse && ((lane & 2) != 0);
            const float alv = cb ? -g : C5, bev = cb ? C5 : g;
            LANE_GATE_DPP("quad_perm:[1,0,3,2]", alv, bev);
        }
        {   // w7 + post C(6,7): reg pairs (r, r+4), ctrl r bit3 (+fuse)
            #pragma unroll
            for (int r = 0; r < 16; ++r) {
                if (r & 4) continue;
                const float lo = A[r], hi = A[r + 4];
                if (fuse && (r & 8)) {
                    A[r]     = fmaf( S7, lo, C7 * hi);
                    A[r + 4] = fmaf(-S7, hi, C7 * lo);
                } else {
                    A[r]     = fmaf(C7, lo, -S7 * hi);
                    A[r + 4] = fmaf(C7, hi,  S7 * lo);
                }
            }
        }
        {   // w9 + post C(8,9): reg pairs (r, r+1), ctrl r bit1 (+fuse)
            #pragma unroll
            for (int r = 0; r < 16; r += 2) {
                const float xv = A[r], yv = A[r + 1];
                if (fuse && (r & 2)) {
                    A[r]     = fmaf( S9, xv, C9 * yv);
                    A[r + 1] = fmaf(-S9, yv, C9 * xv);
                } else {
                    A[r]     = fmaf(C9, xv, -S9 * yv);
                    A[r + 1] = fmaf(C9, yv,  S9 * xv);
                }
            }
        }
    }

    // ---------- expvals <Z_w> ----------
    float tot = 0.f, q6 = 0.f, q7 = 0.f, q8 = 0.f, q9 = 0.f;
    #pragma unroll
    for (int r = 0; r < 16; ++r) {
        const float P = A[r] * A[r];
        tot += P;
        if (r & 8) q6 += P;
        if (r & 4) q7 += P;
        if (r & 2) q8 += P;
        if (r & 1) q9 += P;
    }
    float e[NQ];
    e[0] = (lane & 32) ? -tot : tot;
    e[1] = (lane & 16) ? -tot : tot;
    e[2] = (lane & 8)  ? -tot : tot;
    e[3] = (lane & 4)  ? -tot : tot;
    e[4] = (lane & 2)  ? -tot : tot;
    e[5] = (lane & 1)  ? -tot : tot;
    e[6] = fmaf(-2.f, q6, tot);
    e[7] = fmaf(-2.f, q7, tot);
    e[8] = fmaf(-2.f, q8, tot);
    e[9] = fmaf(-2.f, q9, tot);
    #pragma unroll
    for (int w = 0; w < NQ; ++w) e[w] = red64(e[w], xaddr);

    // ---------- output GEMM: lane = output column ----------
    if (b < B) {
        float o = b2[lane];
        #pragma unroll
        for (int w = 0; w < NQ; ++w) o = fmaf(e[w], W2[w * DOUT + lane], o);
        out[(size_t)b * DOUT + lane] = o;
    }
}

extern "C" void kernel_launch(void* const* d_in, const int* in_sizes, int n_in,
                              void* d_out, int out_size, void* d_ws, size_t ws_size,
                              hipStream_t stream) {
    const float* x  = (const float*)d_in[0];
    const float* W1 = (const float*)d_in[1];
    const float* b1 = (const float*)d_in[2];
    const float* qw = (const float*)d_in[3];
    const float* W2 = (const float*)d_in[4];
    const float* b2 = (const float*)d_in[5];
    float* out = (float*)d_out;

    const int B = in_sizes[0] / DIN;
    const int blocks = (B + 3) / 4;   // 4 samples (waves) per 256-thread block
    dqc_main<<<blocks, 256, 0, stream>>>(x, W1, b1, qw, W2, b2, out, B);
}